// Round 1
// baseline (2263.689 us; speedup 1.0000x reference)
//
#include <hip/hip_runtime.h>
#include <math.h>

// MosfetFNO: B=128, T=4096, pad=410 -> Tp=4506; padded to TPAD=4608 (36*128).
// Workspace need: x(128*64*4608) + xfp(6*8192*128) + coef(128*128*64)
//               + fwdF(4608*128) + invF(128*4608) + latb(128*128)
//               = 46,284,800 floats = 185.2 MB  (assumed <= ws_size)
#define B_     128
#define T_     4096
#define TP_    4506
#define TPAD_  4608
#define KSPLIT 6
#define CPS    12      // chunks of 64 per K-split (6*12*64 = 4608)
#define NL_    4

__device__ __forceinline__ float silu_f(float x){
  return x / (1.0f + expf(-x));
}
__device__ __forceinline__ float gelu_f(float x){
  float u = x + 0.044715f*x*x*x;
  return 0.5f*x*(1.0f + tanhf(0.7978845608028654f*u));
}

#define FMA8x8(ACC, A0, A1, B0, B1) do {                                   \
  float av_[8] = {A0.x,A0.y,A0.z,A0.w,A1.x,A1.y,A1.z,A1.w};                \
  float bv_[8] = {B0.x,B0.y,B0.z,B0.w,B1.x,B1.y,B1.z,B1.w};                \
  _Pragma("unroll")                                                        \
  for(int i_=0;i_<8;i_++){                                                 \
    _Pragma("unroll")                                                      \
    for(int j_=0;j_<8;j_++) ACC[i_][j_] += av_[i_]*bv_[j_];                \
  }                                                                        \
} while(0)

// ---------------------------------------------------------------- tables
// fwdF[t][j]: j<64 -> cos(2*pi*j*t/Tp) ; j>=64 -> -sin(2*pi*(j-64)*t/Tp); 0 for t>=Tp
// invF[k][t]: same values transposed. Rebuilt every launch (ws is poisoned).
__global__ __launch_bounds__(256) void k_tables(float* __restrict__ fwdF,
                                                float* __restrict__ invF){
  int idx = blockIdx.x*256 + threadIdx.x;
  if(idx >= TPAD_*64) return;
  int t = idx >> 6, m = idx & 63;
  float c = 0.f, s = 0.f;
  if(t < TP_){
    int r = (int)(((long long)m * (long long)t) % TP_);
    double ang = 6.283185307179586476925287 * (double)r / (double)TP_;
    c = (float)cos(ang);
    s = (float)sin(ang);
  }
  fwdF[t*128 + m]      = c;
  fwdF[t*128 + 64 + m] = -s;
  invF[(long)m*TPAD_ + t]      = c;
  invF[(long)(64+m)*TPAD_ + t] = -s;
}

// ---------------------------------------------------------------- embed
// h = gelu(p@W1+b1); h = gelu(h@W2+b2); e = tanh(h@W3+b3)
// latb[b][d] = lift_b1[d] + sum_c e[c]*lift_w1[4+c][d]
__global__ __launch_bounds__(128) void k_embed(
    const float* __restrict__ pp,
    const float* __restrict__ ew1, const float* __restrict__ eb1,
    const float* __restrict__ ew2, const float* __restrict__ eb2,
    const float* __restrict__ ew3, const float* __restrict__ eb3,
    const float* __restrict__ lw1, const float* __restrict__ lb1,
    float* __restrict__ latb)
{
  int b = blockIdx.x, tid = threadIdx.x;
  __shared__ float p[64], h1[128], h2[128], e[32];
  if(tid < 64) p[tid] = pp[b*64 + tid];
  __syncthreads();
  {
    float z = eb1[tid];
    for(int j=0;j<64;j++) z += p[j]*ew1[j*128 + tid];
    h1[tid] = gelu_f(z);
  }
  __syncthreads();
  {
    float z = eb2[tid];
    for(int j=0;j<128;j++) z += h1[j]*ew2[j*128 + tid];
    h2[tid] = gelu_f(z);
  }
  __syncthreads();
  if(tid < 32){
    float z = eb3[tid];
    for(int j=0;j<128;j++) z += h2[j]*ew3[j*32 + tid];
    e[tid] = tanhf(z);
  }
  __syncthreads();
  {
    float v = lb1[tid];
    for(int c=0;c<32;c++) v += e[c]*lw1[(4+c)*128 + tid];
    latb[b*128 + tid] = v;
  }
}

// ---------------------------------------------------------------- lift
// x[b][w][t] = lift2( silu( lift1(concat(v[b,:,t], lat[b])) ) ), zeros t>=T
__global__ __launch_bounds__(128) void k_lift(
    const float* __restrict__ vterm, const float* __restrict__ latb,
    const float* __restrict__ lw1,  const float* __restrict__ lw2,
    const float* __restrict__ lb2,  float* __restrict__ x)
{
  int tt = blockIdx.x, b = blockIdx.y, tid = threadIdx.x;
  int t0 = tt*128;
  if(t0 >= T_){ // zero pad region [T, TPAD)
    int r = tid >> 1, tcb = (tid & 1)*64;
    float4 z4 = make_float4(0.f,0.f,0.f,0.f);
    #pragma unroll
    for(int q=0;q<16;q++)
      *(float4*)(x + ((long)b*64 + r)*TPAD_ + t0 + tcb + q*4) = z4;
    return;
  }
  __shared__ float w2s[128*64];   // [d][w]
  __shared__ float zt[64*132];    // [d_local][t] silu(z1)
  __shared__ float vt[4*128];     // [c][t]
  #pragma unroll
  for(int q=0;q<16;q++){
    int idx = q*512 + tid*4;
    *(float4*)(w2s + idx) = *(const float4*)(lw2 + idx);
  }
  {
    int c = tid >> 5, tc = (tid & 31)*4;
    *(float4*)(vt + c*128 + tc) =
      *(const float4*)(vterm + ((long)b*4 + c)*T_ + t0 + tc);
  }
  int tx = tid & 15, ty = tid >> 4;     // t = 8tx, w = 8ty
  float acc[8][8];
  #pragma unroll
  for(int i=0;i<8;i++){
    #pragma unroll
    for(int j=0;j<8;j++) acc[i][j] = 0.f;
  }
  for(int ch=0; ch<2; ++ch){
    __syncthreads();
    { // z1 for d in [ch*64, ch*64+64)
      int dl = tid >> 1, d = ch*64 + dl, tcb = (tid & 1)*64;
      float lb  = latb[b*128 + d];
      float wc0 = lw1[0*128 + d], wc1 = lw1[1*128 + d];
      float wc2 = lw1[2*128 + d], wc3 = lw1[3*128 + d];
      #pragma unroll
      for(int q=0;q<16;q++){
        int tc = tcb + q*4;
        float4 v0 = *(const float4*)(vt + 0*128 + tc);
        float4 v1 = *(const float4*)(vt + 1*128 + tc);
        float4 v2 = *(const float4*)(vt + 2*128 + tc);
        float4 v3 = *(const float4*)(vt + 3*128 + tc);
        float4 z;
        z.x = silu_f(lb + wc0*v0.x + wc1*v1.x + wc2*v2.x + wc3*v3.x);
        z.y = silu_f(lb + wc0*v0.y + wc1*v1.y + wc2*v2.y + wc3*v3.y);
        z.z = silu_f(lb + wc0*v0.z + wc1*v1.z + wc2*v2.z + wc3*v3.z);
        z.w = silu_f(lb + wc0*v0.w + wc1*v1.w + wc2*v2.w + wc3*v3.w);
        *(float4*)(zt + dl*132 + tc) = z;
      }
    }
    __syncthreads();
    #pragma unroll 4
    for(int k=0;k<64;k++){
      int d = ch*64 + k;
      float4 a0 = *(const float4*)(w2s + d*64 + 8*ty);
      float4 a1 = *(const float4*)(w2s + d*64 + 8*ty + 4);
      float4 b0 = *(const float4*)(zt + k*132 + 8*tx);
      float4 b1 = *(const float4*)(zt + k*132 + 8*tx + 4);
      FMA8x8(acc, a0, a1, b0, b1);
    }
  }
  #pragma unroll
  for(int i=0;i<8;i++){
    int w = 8*ty + i;
    float bias = lb2[w];
    float* dst = x + ((long)b*64 + w)*TPAD_ + t0 + 8*tx;
    *(float4*)(dst)   = make_float4(acc[i][0]+bias, acc[i][1]+bias, acc[i][2]+bias, acc[i][3]+bias);
    *(float4*)(dst+4) = make_float4(acc[i][4]+bias, acc[i][5]+bias, acc[i][6]+bias, acc[i][7]+bias);
  }
}

// ---------------------------------------------------------------- forward DFT
// xfp[s][(b*64+c)][j] = partial_k sum_t silu(x[b][c][t]) * fwdF[t][j]
__global__ __launch_bounds__(128) void k_dftfwd(
    const float* __restrict__ x, const float* __restrict__ fwdF,
    float* __restrict__ xfp)
{
  int rowt = blockIdx.x;      // 0..127 (64 rows each)
  int s    = blockIdx.y;      // 0..KSPLIT-1
  int row0 = rowt*64;
  int tid  = threadIdx.x;
  __shared__ float at[64*64];   // [k][r] (transposed, silu applied)
  __shared__ float ft[64*128];  // [k][j]
  int tx = tid & 15, ty = tid >> 4;   // j = 8tx, r = 8ty
  float acc[8][8];
  #pragma unroll
  for(int i=0;i<8;i++){
    #pragma unroll
    for(int j=0;j<8;j++) acc[i][j] = 0.f;
  }
  for(int cc=0; cc<CPS; ++cc){
    int k0 = (s*CPS + cc)*64;
    {
      int r = tid & 63, tq0 = tid >> 6;
      #pragma unroll
      for(int p=0;p<8;p++){
        int tq = tq0 + p*2;
        float4 v = *(const float4*)(x + (long)(row0 + r)*TPAD_ + k0 + tq*4);
        at[(tq*4+0)*64 + r] = silu_f(v.x);
        at[(tq*4+1)*64 + r] = silu_f(v.y);
        at[(tq*4+2)*64 + r] = silu_f(v.z);
        at[(tq*4+3)*64 + r] = silu_f(v.w);
      }
    }
    #pragma unroll
    for(int q=0;q<16;q++){
      int idx = q*512 + tid*4;
      *(float4*)(ft + idx) = *(const float4*)(fwdF + (long)k0*128 + idx);
    }
    __syncthreads();
    #pragma unroll 4
    for(int k=0;k<64;k++){
      float4 a0 = *(const float4*)(at + k*64 + 8*ty);
      float4 a1 = *(const float4*)(at + k*64 + 8*ty + 4);
      float4 f0 = *(const float4*)(ft + k*128 + 8*tx);
      float4 f1 = *(const float4*)(ft + k*128 + 8*tx + 4);
      FMA8x8(acc, a0, a1, f0, f1);
    }
    __syncthreads();
  }
  #pragma unroll
  for(int i=0;i<8;i++){
    int row = row0 + 8*ty + i;
    float* dst = xfp + ((long)s*8192 + row)*128 + 8*tx;
    *(float4*)(dst)   = make_float4(acc[i][0],acc[i][1],acc[i][2],acc[i][3]);
    *(float4*)(dst+4) = make_float4(acc[i][4],acc[i][5],acc[i][6],acc[i][7]);
  }
}

// ---------------------------------------------------------------- spectral mix
// yf[b,o,m] = sum_c xf[b,c,m]*(wr+i*wi)[c,o,m]; store scaled into
// coef[b][k][o]: k=m -> s_m*Re, k=64+m -> s_m*Im   (s_0=1/Tp, s_m=2/Tp)
__global__ __launch_bounds__(512) void k_spectral(
    const float* __restrict__ xfp, const float* __restrict__ wr_,
    const float* __restrict__ wi_, float* __restrict__ coef, int l)
{
  int b = blockIdx.x, mh = blockIdx.y, tid = threadIdx.x;
  const float* wr = wr_ + (long)l*262144;
  const float* wi = wi_ + (long)l*262144;
  __shared__ float xr[64*36], xi[64*36];
  {
    int c = tid >> 3, mm0 = (tid & 7)*4;
    long base = ((long)(b*64 + c))*128 + mh*32 + mm0;
    float4 sr = make_float4(0.f,0.f,0.f,0.f), si = sr;
    #pragma unroll
    for(int s2=0;s2<KSPLIT;s2++){
      const float* p = xfp + (long)s2*1048576 + base;
      float4 a = *(const float4*)(p);
      float4 d = *(const float4*)(p + 64);
      sr.x += a.x; sr.y += a.y; sr.z += a.z; sr.w += a.w;
      si.x += d.x; si.y += d.y; si.z += d.z; si.w += d.w;
    }
    *(float4*)(xr + c*36 + mm0) = sr;
    *(float4*)(xi + c*36 + mm0) = si;
  }
  __syncthreads();
  int tx = tid & 15, ty = tid >> 4;  // m = mh*32+2tx+{0,1}, o = 2ty+{0,1}
  float ar[2][2] = {{0.f,0.f},{0.f,0.f}};
  float ai[2][2] = {{0.f,0.f},{0.f,0.f}};
  #pragma unroll 2
  for(int c=0;c<64;c++){
    float x0r = xr[c*36 + 2*tx], x1r = xr[c*36 + 2*tx + 1];
    float x0i = xi[c*36 + 2*tx], x1i = xi[c*36 + 2*tx + 1];
    #pragma unroll
    for(int oi=0;oi<2;oi++){
      int o = 2*ty + oi;
      long wofs = ((long)(c*64 + o))*64 + mh*32 + 2*tx;
      float2 wrv = *(const float2*)(wr + wofs);
      float2 wiv = *(const float2*)(wi + wofs);
      ar[oi][0] += x0r*wrv.x - x0i*wiv.x;
      ai[oi][0] += x0r*wiv.x + x0i*wrv.x;
      ar[oi][1] += x1r*wrv.y - x1i*wiv.y;
      ai[oi][1] += x1r*wiv.y + x1i*wrv.y;
    }
  }
  #pragma unroll
  for(int j=0;j<2;j++){
    int m = mh*32 + 2*tx + j;
    float sc = (m==0) ? (1.0f/(float)TP_) : (2.0f/(float)TP_);
    #pragma unroll
    for(int oi=0;oi<2;oi++){
      int o = 2*ty + oi;
      coef[((long)b*128 + m)*64 + o]      = sc*ar[oi][j];
      coef[((long)b*128 + 64 + m)*64 + o] = sc*ai[oi][j];
    }
  }
}

// ---------------------------------------------------------------- inverse DFT + skip (in place)
// x[b][o][t] = sum_k coef[b][k][o]*invF[k][t] + sum_c skw[o][c]*silu(x[b][c][t]) + skb[o]
// (0 for t >= Tp). In place: each block consumes exactly the region it writes.
__global__ __launch_bounds__(128) void k_idft_skip(
    float* __restrict__ x, const float* __restrict__ coef,
    const float* __restrict__ invF, const float* __restrict__ sw_,
    const float* __restrict__ sb_, int l)
{
  int tt = blockIdx.x, b = blockIdx.y, tid = threadIdx.x;
  int t0 = tt*128;
  const float* sw = sw_ + l*4096;
  const float* sb = sb_ + l*64;
  __shared__ float bufA[64*64];    // coef chunk [k][o], then swT [c][o]
  __shared__ float bufB[64*132];   // invF chunk [k][t], then hpre [c][t]
  int tx = tid & 15, ty = tid >> 4;   // t = 8tx, o = 8ty
  float acc[8][8];
  #pragma unroll
  for(int i=0;i<8;i++){
    #pragma unroll
    for(int j=0;j<8;j++) acc[i][j] = 0.f;
  }
  for(int kc=0;kc<2;kc++){
    if(kc) __syncthreads();
    #pragma unroll
    for(int q=0;q<8;q++){
      int idx = q*512 + tid*4;
      *(float4*)(bufA + idx) = *(const float4*)(coef + ((long)b*128 + kc*64)*64 + idx);
    }
    {
      int kk = tid >> 1, tcb = (tid & 1)*64;
      #pragma unroll
      for(int q=0;q<16;q++){
        int tc = tcb + q*4;
        *(float4*)(bufB + kk*132 + tc) =
          *(const float4*)(invF + (long)(kc*64 + kk)*TPAD_ + t0 + tc);
      }
    }
    __syncthreads();
    #pragma unroll 4
    for(int k=0;k<64;k++){
      float4 a0 = *(const float4*)(bufA + k*64 + 8*ty);
      float4 a1 = *(const float4*)(bufA + k*64 + 8*ty + 4);
      float4 b0 = *(const float4*)(bufB + k*132 + 8*tx);
      float4 b1 = *(const float4*)(bufB + k*132 + 8*tx + 4);
      FMA8x8(acc, a0, a1, b0, b1);
    }
  }
  __syncthreads();
  { // stage skip operands
    int o = tid >> 1, chh = (tid & 1)*32;
    #pragma unroll
    for(int q=0;q<8;q++){
      int c0 = chh + q*4;
      float4 v = *(const float4*)(sw + o*64 + c0);
      bufA[(c0+0)*64 + o] = v.x;
      bufA[(c0+1)*64 + o] = v.y;
      bufA[(c0+2)*64 + o] = v.z;
      bufA[(c0+3)*64 + o] = v.w;
    }
    int c = tid >> 1, tcb = (tid & 1)*64;
    #pragma unroll
    for(int q=0;q<16;q++){
      int tc = tcb + q*4;
      float4 v = *(const float4*)(x + ((long)b*64 + c)*TPAD_ + t0 + tc);
      float4 h;
      h.x = silu_f(v.x); h.y = silu_f(v.y); h.z = silu_f(v.z); h.w = silu_f(v.w);
      *(float4*)(bufB + c*132 + tc) = h;
    }
  }
  __syncthreads();
  #pragma unroll 4
  for(int k=0;k<64;k++){
    float4 a0 = *(const float4*)(bufA + k*64 + 8*ty);
    float4 a1 = *(const float4*)(bufA + k*64 + 8*ty + 4);
    float4 b0 = *(const float4*)(bufB + k*132 + 8*tx);
    float4 b1 = *(const float4*)(bufB + k*132 + 8*tx + 4);
    FMA8x8(acc, a0, a1, b0, b1);
  }
  #pragma unroll
  for(int i=0;i<8;i++){
    int o = 8*ty + i;
    float bias = sb[o];
    float* dst = x + ((long)b*64 + o)*TPAD_ + t0 + 8*tx;
    int tg = t0 + 8*tx;
    float v[8];
    #pragma unroll
    for(int j=0;j<8;j++) v[j] = (tg + j < TP_) ? (acc[i][j] + bias) : 0.f;
    *(float4*)(dst)   = make_float4(v[0],v[1],v[2],v[3]);
    *(float4*)(dst+4) = make_float4(v[4],v[5],v[6],v[7]);
  }
}

// ---------------------------------------------------------------- projection
// out[b][t] = pb2 + sum_d pw2[d]*silu( sum_w x[b][w][t]*pw1[w][d] + pb1[d] )
__global__ __launch_bounds__(256) void k_proj(
    const float* __restrict__ x,  const float* __restrict__ pw1,
    const float* __restrict__ pb1, const float* __restrict__ pw2,
    const float* __restrict__ pb2, float* __restrict__ out)
{
  int tt = blockIdx.x, b = blockIdx.y, tid = threadIdx.x;
  int t0 = tt*128;
  __shared__ float w1s[64*128];   // [w][d]
  __shared__ float xt[64*132];    // [w][t]
  __shared__ float red[16*132];
  #pragma unroll
  for(int q=0;q<8;q++){
    int idx = q*1024 + tid*4;
    *(float4*)(w1s + idx) = *(const float4*)(pw1 + idx);
  }
  {
    int w = tid >> 2, tc0 = (tid & 3)*4;
    #pragma unroll
    for(int q=0;q<8;q++){
      int tc = tc0 + q*16;
      *(float4*)(xt + w*132 + tc) =
        *(const float4*)(x + ((long)b*64 + w)*TPAD_ + t0 + tc);
    }
  }
  __syncthreads();
  int tx = tid & 15, ty = tid >> 4;   // t = 8tx, d = 8ty
  float acc[8][8];
  #pragma unroll
  for(int i=0;i<8;i++){
    #pragma unroll
    for(int j=0;j<8;j++) acc[i][j] = 0.f;
  }
  #pragma unroll 4
  for(int k=0;k<64;k++){
    float4 a0 = *(const float4*)(w1s + k*128 + 8*ty);
    float4 a1 = *(const float4*)(w1s + k*128 + 8*ty + 4);
    float4 b0 = *(const float4*)(xt + k*132 + 8*tx);
    float4 b1 = *(const float4*)(xt + k*132 + 8*tx + 4);
    FMA8x8(acc, a0, a1, b0, b1);
  }
  float part[8];
  #pragma unroll
  for(int j=0;j<8;j++) part[j] = 0.f;
  #pragma unroll
  for(int i=0;i<8;i++){
    int d = 8*ty + i;
    float bb = pb1[d], w2v = pw2[d];
    #pragma unroll
    for(int j=0;j<8;j++) part[j] += w2v * silu_f(acc[i][j] + bb);
  }
  *(float4*)(red + ty*132 + 8*tx)     = make_float4(part[0],part[1],part[2],part[3]);
  *(float4*)(red + ty*132 + 8*tx + 4) = make_float4(part[4],part[5],part[6],part[7]);
  __syncthreads();
  if(tid < 128){
    float ssum = pb2[0];
    #pragma unroll
    for(int y=0;y<16;y++) ssum += red[y*132 + tid];
    out[(long)b*T_ + t0 + tid] = ssum;
  }
}

// ---------------------------------------------------------------- launch
extern "C" void kernel_launch(void* const* d_in, const int* in_sizes, int n_in,
                              void* d_out, int out_size, void* d_ws, size_t ws_size,
                              hipStream_t stream)
{
  const float* vterm = (const float*)d_in[0];
  const float* pp    = (const float*)d_in[1];
  const float* ew1   = (const float*)d_in[2];
  const float* eb1   = (const float*)d_in[3];
  const float* ew2   = (const float*)d_in[4];
  const float* eb2   = (const float*)d_in[5];
  const float* ew3   = (const float*)d_in[6];
  const float* eb3   = (const float*)d_in[7];
  const float* lw1   = (const float*)d_in[8];
  const float* lb1   = (const float*)d_in[9];
  const float* lw2   = (const float*)d_in[10];
  const float* lb2   = (const float*)d_in[11];
  const float* swr   = (const float*)d_in[12];
  const float* swi   = (const float*)d_in[13];
  const float* skw   = (const float*)d_in[14];
  const float* skb   = (const float*)d_in[15];
  const float* pw1   = (const float*)d_in[16];
  const float* pb1   = (const float*)d_in[17];
  const float* pw2   = (const float*)d_in[18];
  const float* pb2   = (const float*)d_in[19];
  float* out = (float*)d_out;
  float* ws  = (float*)d_ws;

  float* x    = ws;
  float* xfp  = x    + (long)B_*64*TPAD_;
  float* coef = xfp  + (long)KSPLIT*8192*128;
  float* fwdF = coef + (long)B_*128*64;
  float* invF = fwdF + (long)TPAD_*128;
  float* latb = invF + (long)128*TPAD_;

  k_tables<<<(TPAD_*64 + 255)/256, 256, 0, stream>>>(fwdF, invF);
  k_embed<<<B_, 128, 0, stream>>>(pp, ew1, eb1, ew2, eb2, ew3, eb3, lw1, lb1, latb);
  k_lift<<<dim3(TPAD_/128, B_), 128, 0, stream>>>(vterm, latb, lw1, lw2, lb2, x);
  for(int l=0;l<NL_;l++){
    k_dftfwd<<<dim3(128, KSPLIT), 128, 0, stream>>>(x, fwdF, xfp);
    k_spectral<<<dim3(B_, 2), 512, 0, stream>>>(xfp, swr, swi, coef, l);
    k_idft_skip<<<dim3(TPAD_/128, B_), 128, 0, stream>>>(x, coef, invF, skw, skb, l);
  }
  k_proj<<<dim3(T_/128, B_), 256, 0, stream>>>(x, pw1, pb1, pw2, pb2, out);
}

// Round 2
// 1378.599 us; speedup vs baseline: 1.6420x; 1.6420x over previous
//
#include <hip/hip_runtime.h>
#include <math.h>

// MosfetFNO on MI355X — MFMA (bf16 hi/lo 3-product emulation) version.
// B=128, T=4096, pad=410 -> Tp=4506; padded to TPAD=4608.
// ws layout (byte-identical total to prev round: 185,139,200 B):
//   x    f32 [128][64][4608]      150,994,944 B
//   xfp  f32 [6][8192][128]        25,165,824 B
//   coefh/l u16 [128][64][128]      2×2,097,152 B   (latb f32 aliases coefh)
//   fwdFh/l u16 [4608][128]         2×1,179,648 B   ([t][k] trig, iDFT B-op)
//   invFh/l u16 [128][4608]         2×1,179,648 B   ([j][t] trig, fwd-DFT B-op)
//   skwh/l  u16 [4][64][64]         2×32,768 B
#define B_     128
#define T_     4096
#define TP_    4506
#define TPAD_  4608
#define KSPLIT 6
#define NL_    4

typedef __attribute__((ext_vector_type(8))) short bf16x8;
typedef __attribute__((ext_vector_type(4))) float f32x4;
typedef unsigned short u16;

__device__ __forceinline__ float silu_f(float x){
  return x / (1.0f + expf(-x));
}
__device__ __forceinline__ float gelu_f(float x){
  float u = x + 0.044715f*x*x*x;
  return 0.5f*x*(1.0f + tanhf(0.7978845608028654f*u));
}
__device__ __forceinline__ u16 bf16_rne(float f){
  unsigned u = __float_as_uint(f);
  unsigned r = u + 0x7FFFu + ((u >> 16) & 1u);
  return (u16)(r >> 16);
}
__device__ __forceinline__ void bf16_split(float f, u16& h, u16& l){
  h = bf16_rne(f);
  float fh = __uint_as_float(((unsigned)h) << 16);
  l = bf16_rne(f - fh);
}
__device__ __forceinline__ void silu_split(float v, u16& h, u16& l){
  float s = v / (1.0f + __expf(-v));
  bf16_split(s, h, l);
}
__device__ __forceinline__ f32x4 mfma16(bf16x8 a, bf16x8 b, f32x4 c){
  return __builtin_amdgcn_mfma_f32_16x16x32_bf16(a, b, c, 0, 0, 0);
}

#define FMA8x8(ACC, A0, A1, B0, B1) do {                                   \
  float av_[8] = {A0.x,A0.y,A0.z,A0.w,A1.x,A1.y,A1.z,A1.w};                \
  float bv_[8] = {B0.x,B0.y,B0.z,B0.w,B1.x,B1.y,B1.z,B1.w};                \
  _Pragma("unroll")                                                        \
  for(int i_=0;i_<8;i_++){                                                 \
    _Pragma("unroll")                                                      \
    for(int j_=0;j_<8;j_++) ACC[i_][j_] += av_[i_]*bv_[j_];                \
  }                                                                        \
} while(0)

// ---------------------------------------------------------------- tables
// fwdF*[t][k]: k<64 cos(2pi k t/Tp), k>=64 -sin;  0 for t>=Tp.
// invF*[j][t]: same values, [j][t] layout.
__global__ __launch_bounds__(256) void k_tables(u16* __restrict__ fwdFh,
    u16* __restrict__ fwdFl, u16* __restrict__ invFh, u16* __restrict__ invFl){
  int idx = blockIdx.x*256 + threadIdx.x;
  if(idx >= TPAD_*64) return;
  int t = idx >> 6, m = idx & 63;
  float c = 0.f, s = 0.f;
  if(t < TP_){
    int r = (int)(((long long)m * (long long)t) % TP_);
    double ang = 6.283185307179586476925287 * (double)r / (double)TP_;
    c = (float)cos(ang);
    s = -(float)sin(ang);
  }
  u16 ch, cl, sh, sl;
  bf16_split(c, ch, cl);
  bf16_split(s, sh, sl);
  fwdFh[t*128 + m] = ch;      fwdFl[t*128 + m] = cl;
  fwdFh[t*128 + 64 + m] = sh; fwdFl[t*128 + 64 + m] = sl;
  invFh[(long)m*TPAD_ + t] = ch;      invFl[(long)m*TPAD_ + t] = cl;
  invFh[(long)(64+m)*TPAD_ + t] = sh; invFl[(long)(64+m)*TPAD_ + t] = sl;
}

// skip weights -> bf16 hi/lo
__global__ __launch_bounds__(256) void k_prep(const float* __restrict__ skw,
    u16* __restrict__ skwh, u16* __restrict__ skwl){
  int i = blockIdx.x*256 + threadIdx.x;
  if(i >= NL_*64*64) return;
  u16 h, l; bf16_split(skw[i], h, l);
  skwh[i] = h; skwl[i] = l;
}

// ---------------------------------------------------------------- embed
__global__ __launch_bounds__(128) void k_embed(
    const float* __restrict__ pp,
    const float* __restrict__ ew1, const float* __restrict__ eb1,
    const float* __restrict__ ew2, const float* __restrict__ eb2,
    const float* __restrict__ ew3, const float* __restrict__ eb3,
    const float* __restrict__ lw1, const float* __restrict__ lb1,
    float* __restrict__ latb)
{
  int b = blockIdx.x, tid = threadIdx.x;
  __shared__ float p[64], h1[128], h2[128], e[32];
  if(tid < 64) p[tid] = pp[b*64 + tid];
  __syncthreads();
  {
    float z = eb1[tid];
    for(int j=0;j<64;j++) z += p[j]*ew1[j*128 + tid];
    h1[tid] = gelu_f(z);
  }
  __syncthreads();
  {
    float z = eb2[tid];
    for(int j=0;j<128;j++) z += h1[j]*ew2[j*128 + tid];
    h2[tid] = gelu_f(z);
  }
  __syncthreads();
  if(tid < 32){
    float z = eb3[tid];
    for(int j=0;j<128;j++) z += h2[j]*ew3[j*32 + tid];
    e[tid] = tanhf(z);
  }
  __syncthreads();
  {
    float v = lb1[tid];
    for(int c=0;c<32;c++) v += e[c]*lw1[(4+c)*128 + tid];
    latb[b*128 + tid] = v;
  }
}

// ---------------------------------------------------------------- lift (fp32)
__global__ __launch_bounds__(128) void k_lift(
    const float* __restrict__ vterm, const float* __restrict__ latb,
    const float* __restrict__ lw1,  const float* __restrict__ lw2,
    const float* __restrict__ lb2,  float* __restrict__ x)
{
  int tt = blockIdx.x, b = blockIdx.y, tid = threadIdx.x;
  int t0 = tt*128;
  if(t0 >= T_){
    int r = tid >> 1, tcb = (tid & 1)*64;
    float4 z4 = make_float4(0.f,0.f,0.f,0.f);
    #pragma unroll
    for(int q=0;q<16;q++)
      *(float4*)(x + ((long)b*64 + r)*TPAD_ + t0 + tcb + q*4) = z4;
    return;
  }
  __shared__ float w2s[128*64];
  __shared__ float zt[64*132];
  __shared__ float vt[4*128];
  #pragma unroll
  for(int q=0;q<16;q++){
    int idx = q*512 + tid*4;
    *(float4*)(w2s + idx) = *(const float4*)(lw2 + idx);
  }
  {
    int c = tid >> 5, tc = (tid & 31)*4;
    *(float4*)(vt + c*128 + tc) =
      *(const float4*)(vterm + ((long)b*4 + c)*T_ + t0 + tc);
  }
  int tx = tid & 15, ty = tid >> 4;
  float acc[8][8];
  #pragma unroll
  for(int i=0;i<8;i++){
    #pragma unroll
    for(int j=0;j<8;j++) acc[i][j] = 0.f;
  }
  for(int ch=0; ch<2; ++ch){
    __syncthreads();
    {
      int dl = tid >> 1, d = ch*64 + dl, tcb = (tid & 1)*64;
      float lb  = latb[b*128 + d];
      float wc0 = lw1[0*128 + d], wc1 = lw1[1*128 + d];
      float wc2 = lw1[2*128 + d], wc3 = lw1[3*128 + d];
      #pragma unroll
      for(int q=0;q<16;q++){
        int tc = tcb + q*4;
        float4 v0 = *(const float4*)(vt + 0*128 + tc);
        float4 v1 = *(const float4*)(vt + 1*128 + tc);
        float4 v2 = *(const float4*)(vt + 2*128 + tc);
        float4 v3 = *(const float4*)(vt + 3*128 + tc);
        float4 z;
        z.x = silu_f(lb + wc0*v0.x + wc1*v1.x + wc2*v2.x + wc3*v3.x);
        z.y = silu_f(lb + wc0*v0.y + wc1*v1.y + wc2*v2.y + wc3*v3.y);
        z.z = silu_f(lb + wc0*v0.z + wc1*v1.z + wc2*v2.z + wc3*v3.z);
        z.w = silu_f(lb + wc0*v0.w + wc1*v1.w + wc2*v2.w + wc3*v3.w);
        *(float4*)(zt + dl*132 + tc) = z;
      }
    }
    __syncthreads();
    #pragma unroll 4
    for(int k=0;k<64;k++){
      int d = ch*64 + k;
      float4 a0 = *(const float4*)(w2s + d*64 + 8*ty);
      float4 a1 = *(const float4*)(w2s + d*64 + 8*ty + 4);
      float4 b0 = *(const float4*)(zt + k*132 + 8*tx);
      float4 b1 = *(const float4*)(zt + k*132 + 8*tx + 4);
      FMA8x8(acc, a0, a1, b0, b1);
    }
  }
  #pragma unroll
  for(int i=0;i<8;i++){
    int w = 8*ty + i;
    float bias = lb2[w];
    float* dst = x + ((long)b*64 + w)*TPAD_ + t0 + 8*tx;
    *(float4*)(dst)   = make_float4(acc[i][0]+bias, acc[i][1]+bias, acc[i][2]+bias, acc[i][3]+bias);
    *(float4*)(dst+4) = make_float4(acc[i][4]+bias, acc[i][5]+bias, acc[i][6]+bias, acc[i][7]+bias);
  }
}

// ---------------------------------------------------------------- forward DFT (MFMA)
// xfp[s][(b*64+c)][j] = sum_{t in split s} silu(x[b][c][t]) * F[t][j]
// A = silu(x) [c][t] (LDS, swizzled, hi/lo), B = invF [j][t] (global bf16 hi/lo).
__global__ __launch_bounds__(256) void k_dft_mfma(
    const float* __restrict__ x, const u16* __restrict__ invFh,
    const u16* __restrict__ invFl, float* __restrict__ xfp)
{
  int b = blockIdx.x, s = blockIdx.y;
  int tid = threadIdx.x;
  int lane = tid & 63, w = tid >> 6;
  int l15 = lane & 15, lhi = lane >> 4;
  int n0 = w*32;
  __shared__ u16 ah[64*128];   // [c][t] bf16-hi, byte ^ ((c&7)<<4)
  __shared__ u16 al[64*128];
  f32x4 acc[4][2];
  #pragma unroll
  for(int mi=0;mi<4;mi++){
    #pragma unroll
    for(int ni=0;ni<2;ni++) acc[mi][ni] = (f32x4){0.f,0.f,0.f,0.f};
  }
  for(int ch=0; ch<6; ++ch){
    int k0 = s*768 + ch*128;
    __syncthreads();
    { // stage silu(x) -> bf16 hi/lo, [c][t-chunk]
      int c = tid >> 2;
      const float* xr = x + ((long)b*64 + c)*TPAD_ + k0;
      int swz = (c & 7) << 4;
      #pragma unroll
      for(int q=0;q<8;q++){
        int tl = ((tid & 3) + 4*q)*4;
        float4 v = *(const float4*)(xr + tl);
        ushort4 hv, lv;
        silu_split(v.x, hv.x, lv.x);
        silu_split(v.y, hv.y, lv.y);
        silu_split(v.z, hv.z, lv.z);
        silu_split(v.w, hv.w, lv.w);
        int byt = (c*256 + tl*2) ^ swz;
        *(ushort4*)((char*)ah + byt) = hv;
        *(ushort4*)((char*)al + byt) = lv;
      }
    }
    __syncthreads();
    #pragma unroll
    for(int ks=0; ks<4; ++ks){
      bf16x8 Ah[4], Al[4], Bh[2], Bl[2];
      #pragma unroll
      for(int mi=0;mi<4;mi++){
        int c = mi*16 + l15;
        int byt = (c*256 + (ks*32 + lhi*8)*2) ^ ((c & 7) << 4);
        Ah[mi] = *(bf16x8*)((char*)ah + byt);
        Al[mi] = *(bf16x8*)((char*)al + byt);
      }
      #pragma unroll
      for(int ni=0;ni<2;ni++){
        int j = n0 + ni*16 + l15;
        long off = (long)j*TPAD_ + k0 + ks*32 + lhi*8;
        Bh[ni] = *(const bf16x8*)(invFh + off);
        Bl[ni] = *(const bf16x8*)(invFl + off);
      }
      #pragma unroll
      for(int mi=0;mi<4;mi++){
        #pragma unroll
        for(int ni=0;ni<2;ni++){
          acc[mi][ni] = mfma16(Ah[mi], Bh[ni], acc[mi][ni]);
          acc[mi][ni] = mfma16(Al[mi], Bh[ni], acc[mi][ni]);
          acc[mi][ni] = mfma16(Ah[mi], Bl[ni], acc[mi][ni]);
        }
      }
    }
  }
  #pragma unroll
  for(int mi=0;mi<4;mi++){
    #pragma unroll
    for(int ni=0;ni<2;ni++){
      #pragma unroll
      for(int r=0;r<4;r++){
        int row = mi*16 + lhi*4 + r;
        int j = n0 + ni*16 + l15;
        xfp[((long)s*8192 + b*64 + row)*128 + j] = acc[mi][ni][r];
      }
    }
  }
}

// ---------------------------------------------------------------- spectral mix
// coef[b][o][k] (bf16 hi/lo): k=m -> s_m*Re(yf), k=64+m -> s_m*Im(yf)
__global__ __launch_bounds__(512) void k_spectral(
    const float* __restrict__ xfp, const float* __restrict__ wr_,
    const float* __restrict__ wi_, u16* __restrict__ coefh,
    u16* __restrict__ coefl, int l)
{
  int b = blockIdx.x, mh = blockIdx.y, tid = threadIdx.x;
  const float* wr = wr_ + (long)l*262144;
  const float* wi = wi_ + (long)l*262144;
  __shared__ float xr[64*36], xi[64*36];
  {
    int c = tid >> 3, mm0 = (tid & 7)*4;
    long base = ((long)(b*64 + c))*128 + mh*32 + mm0;
    float4 sr = make_float4(0.f,0.f,0.f,0.f), si = sr;
    #pragma unroll
    for(int s2=0;s2<KSPLIT;s2++){
      const float* p = xfp + (long)s2*1048576 + base;
      float4 a = *(const float4*)(p);
      float4 d = *(const float4*)(p + 64);
      sr.x += a.x; sr.y += a.y; sr.z += a.z; sr.w += a.w;
      si.x += d.x; si.y += d.y; si.z += d.z; si.w += d.w;
    }
    *(float4*)(xr + c*36 + mm0) = sr;
    *(float4*)(xi + c*36 + mm0) = si;
  }
  __syncthreads();
  int tx = tid & 15, ty = tid >> 4;
  float ar[2][2] = {{0.f,0.f},{0.f,0.f}};
  float ai[2][2] = {{0.f,0.f},{0.f,0.f}};
  #pragma unroll 2
  for(int c=0;c<64;c++){
    float x0r = xr[c*36 + 2*tx], x1r = xr[c*36 + 2*tx + 1];
    float x0i = xi[c*36 + 2*tx], x1i = xi[c*36 + 2*tx + 1];
    #pragma unroll
    for(int oi=0;oi<2;oi++){
      int o = 2*ty + oi;
      long wofs = ((long)(c*64 + o))*64 + mh*32 + 2*tx;
      float2 wrv = *(const float2*)(wr + wofs);
      float2 wiv = *(const float2*)(wi + wofs);
      ar[oi][0] += x0r*wrv.x - x0i*wiv.x;
      ai[oi][0] += x0r*wiv.x + x0i*wrv.x;
      ar[oi][1] += x1r*wrv.y - x1i*wiv.y;
      ai[oi][1] += x1r*wiv.y + x1i*wrv.y;
    }
  }
  #pragma unroll
  for(int j=0;j<2;j++){
    int m = mh*32 + 2*tx + j;
    float sc = (m==0) ? (1.0f/(float)TP_) : (2.0f/(float)TP_);
    #pragma unroll
    for(int oi=0;oi<2;oi++){
      int o = 2*ty + oi;
      long base = ((long)b*64 + o)*128;
      u16 h, l2;
      bf16_split(sc*ar[oi][j], h, l2);
      coefh[base + m] = h; coefl[base + m] = l2;
      bf16_split(sc*ai[oi][j], h, l2);
      coefh[base + 64 + m] = h; coefl[base + 64 + m] = l2;
    }
  }
}

// ---------------------------------------------------------------- inverse DFT + skip (MFMA, in place)
// x[b][o][t] = sum_k coef[b][o][k]*F[t][k] + sum_c skw[o][c]*silu(x[b][c][t]) + skb[o]
__global__ __launch_bounds__(256) void k_idft_mfma(
    float* __restrict__ x, const u16* __restrict__ coefh,
    const u16* __restrict__ coefl, const u16* __restrict__ fwdFh,
    const u16* __restrict__ fwdFl, const u16* __restrict__ skwh,
    const u16* __restrict__ skwl, const float* __restrict__ sb_, int lay)
{
  int tt = blockIdx.x, b = blockIdx.y, tid = threadIdx.x;
  int t0 = tt*128;
  int lane = tid & 63, w = tid >> 6;
  int l15 = lane & 15, lhi = lane >> 4;
  int n0 = w*32;
  __shared__ u16 hh[128*64];   // [t][c] bf16-hi, byte ^ ((t&7)<<4)
  __shared__ u16 hl[128*64];
  { // stage H = silu(x) transposed
    int cp = tid & 31, tg = tid >> 3 >> 2;  // tg = tid>>5
    int c0 = cp*2;
    const float* xr0 = x + ((long)b*64 + c0)*TPAD_ + t0 + tg*16;
    const float* xr1 = xr0 + TPAD_;
    #pragma unroll
    for(int q=0;q<4;q++){
      float4 v0 = *(const float4*)(xr0 + q*4);
      float4 v1 = *(const float4*)(xr1 + q*4);
      float e0[4] = {v0.x, v0.y, v0.z, v0.w};
      float e1[4] = {v1.x, v1.y, v1.z, v1.w};
      #pragma unroll
      for(int i=0;i<4;i++){
        int t = tg*16 + q*4 + i;
        u16 h0, l0, h1, l1;
        silu_split(e0[i], h0, l0);
        silu_split(e1[i], h1, l1);
        int byt = (t*128 + c0*2) ^ ((t & 7) << 4);
        *(ushort2*)((char*)hh + byt) = make_ushort2(h0, h1);
        *(ushort2*)((char*)hl + byt) = make_ushort2(l0, l1);
      }
    }
  }
  f32x4 acc[4][2];
  #pragma unroll
  for(int mi=0;mi<4;mi++){
    #pragma unroll
    for(int ni=0;ni<2;ni++) acc[mi][ni] = (f32x4){0.f,0.f,0.f,0.f};
  }
  // phase 1: spectral part, K=128 (coef x trig), all global frags
  #pragma unroll
  for(int ks=0; ks<4; ++ks){
    bf16x8 Ah[4], Al[4], Bh[2], Bl[2];
    #pragma unroll
    for(int mi=0;mi<4;mi++){
      int o = mi*16 + l15;
      long off = ((long)(b*64 + o))*128 + ks*32 + lhi*8;
      Ah[mi] = *(const bf16x8*)(coefh + off);
      Al[mi] = *(const bf16x8*)(coefl + off);
    }
    #pragma unroll
    for(int ni=0;ni<2;ni++){
      int t = t0 + n0 + ni*16 + l15;
      long off = (long)t*128 + ks*32 + lhi*8;
      Bh[ni] = *(const bf16x8*)(fwdFh + off);
      Bl[ni] = *(const bf16x8*)(fwdFl + off);
    }
    #pragma unroll
    for(int mi=0;mi<4;mi++){
      #pragma unroll
      for(int ni=0;ni<2;ni++){
        acc[mi][ni] = mfma16(Ah[mi], Bh[ni], acc[mi][ni]);
        acc[mi][ni] = mfma16(Al[mi], Bh[ni], acc[mi][ni]);
        acc[mi][ni] = mfma16(Ah[mi], Bl[ni], acc[mi][ni]);
      }
    }
  }
  __syncthreads();
  // phase 2: skip GEMM, K=64 (skw x silu(x)), B from LDS
  #pragma unroll
  for(int ks=0; ks<2; ++ks){
    bf16x8 Ah[4], Al[4], Bh[2], Bl[2];
    #pragma unroll
    for(int mi=0;mi<4;mi++){
      int o = mi*16 + l15;
      long off = (long)lay*4096 + o*64 + ks*32 + lhi*8;
      Ah[mi] = *(const bf16x8*)(skwh + off);
      Al[mi] = *(const bf16x8*)(skwl + off);
    }
    #pragma unroll
    for(int ni=0;ni<2;ni++){
      int t = n0 + ni*16 + l15;
      int byt = (t*128 + (ks*32 + lhi*8)*2) ^ ((t & 7) << 4);
      Bh[ni] = *(bf16x8*)((char*)hh + byt);
      Bl[ni] = *(bf16x8*)((char*)hl + byt);
    }
    #pragma unroll
    for(int mi=0;mi<4;mi++){
      #pragma unroll
      for(int ni=0;ni<2;ni++){
        acc[mi][ni] = mfma16(Ah[mi], Bh[ni], acc[mi][ni]);
        acc[mi][ni] = mfma16(Al[mi], Bh[ni], acc[mi][ni]);
        acc[mi][ni] = mfma16(Ah[mi], Bl[ni], acc[mi][ni]);
      }
    }
  }
  // store (in place), zero beyond Tp
  #pragma unroll
  for(int mi=0;mi<4;mi++){
    #pragma unroll
    for(int ni=0;ni<2;ni++){
      #pragma unroll
      for(int r=0;r<4;r++){
        int o = mi*16 + lhi*4 + r;
        int t = t0 + n0 + ni*16 + l15;
        float v = acc[mi][ni][r] + sb_[lay*64 + o];
        if(t >= TP_) v = 0.f;
        x[((long)b*64 + o)*TPAD_ + t] = v;
      }
    }
  }
}

// ---------------------------------------------------------------- projection (fp32)
__global__ __launch_bounds__(256) void k_proj(
    const float* __restrict__ x,  const float* __restrict__ pw1,
    const float* __restrict__ pb1, const float* __restrict__ pw2,
    const float* __restrict__ pb2, float* __restrict__ out)
{
  int tt = blockIdx.x, b = blockIdx.y, tid = threadIdx.x;
  int t0 = tt*128;
  __shared__ float w1s[64*128];
  __shared__ float xt[64*132];
  __shared__ float red[16*132];
  #pragma unroll
  for(int q=0;q<8;q++){
    int idx = q*1024 + tid*4;
    *(float4*)(w1s + idx) = *(const float4*)(pw1 + idx);
  }
  {
    int w = tid >> 2, tc0 = (tid & 3)*4;
    #pragma unroll
    for(int q=0;q<8;q++){
      int tc = tc0 + q*16;
      *(float4*)(xt + w*132 + tc) =
        *(const float4*)(x + ((long)b*64 + w)*TPAD_ + t0 + tc);
    }
  }
  __syncthreads();
  int tx = tid & 15, ty = tid >> 4;
  float acc[8][8];
  #pragma unroll
  for(int i=0;i<8;i++){
    #pragma unroll
    for(int j=0;j<8;j++) acc[i][j] = 0.f;
  }
  #pragma unroll 4
  for(int k=0;k<64;k++){
    float4 a0 = *(const float4*)(w1s + k*128 + 8*ty);
    float4 a1 = *(const float4*)(w1s + k*128 + 8*ty + 4);
    float4 b0 = *(const float4*)(xt + k*132 + 8*tx);
    float4 b1 = *(const float4*)(xt + k*132 + 8*tx + 4);
    FMA8x8(acc, a0, a1, b0, b1);
  }
  float part[8];
  #pragma unroll
  for(int j=0;j<8;j++) part[j] = 0.f;
  #pragma unroll
  for(int i=0;i<8;i++){
    int d = 8*ty + i;
    float bb = pb1[d], w2v = pw2[d];
    #pragma unroll
    for(int j=0;j<8;j++) part[j] += w2v * silu_f(acc[i][j] + bb);
  }
  *(float4*)(red + ty*132 + 8*tx)     = make_float4(part[0],part[1],part[2],part[3]);
  *(float4*)(red + ty*132 + 8*tx + 4) = make_float4(part[4],part[5],part[6],part[7]);
  __syncthreads();
  if(tid < 128){
    float ssum = pb2[0];
    #pragma unroll
    for(int y=0;y<16;y++) ssum += red[y*132 + tid];
    out[(long)b*T_ + t0 + tid] = ssum;
  }
}

// ---------------------------------------------------------------- launch
extern "C" void kernel_launch(void* const* d_in, const int* in_sizes, int n_in,
                              void* d_out, int out_size, void* d_ws, size_t ws_size,
                              hipStream_t stream)
{
  const float* vterm = (const float*)d_in[0];
  const float* pp    = (const float*)d_in[1];
  const float* ew1   = (const float*)d_in[2];
  const float* eb1   = (const float*)d_in[3];
  const float* ew2   = (const float*)d_in[4];
  const float* eb2   = (const float*)d_in[5];
  const float* ew3   = (const float*)d_in[6];
  const float* eb3   = (const float*)d_in[7];
  const float* lw1   = (const float*)d_in[8];
  const float* lb1   = (const float*)d_in[9];
  const float* lw2   = (const float*)d_in[10];
  const float* lb2   = (const float*)d_in[11];
  const float* swr   = (const float*)d_in[12];
  const float* swi   = (const float*)d_in[13];
  const float* skw   = (const float*)d_in[14];
  const float* skb   = (const float*)d_in[15];
  const float* pw1   = (const float*)d_in[16];
  const float* pb1   = (const float*)d_in[17];
  const float* pw2   = (const float*)d_in[18];
  const float* pb2   = (const float*)d_in[19];
  float* out = (float*)d_out;
  float* ws  = (float*)d_ws;

  float* x    = ws;
  float* xfp  = x + (long)B_*64*TPAD_;
  u16* coefh  = (u16*)(xfp + (long)KSPLIT*8192*128);
  u16* coefl  = coefh + 1048576;
  u16* fwdFh  = coefl + 1048576;
  u16* fwdFl  = fwdFh + 589824;
  u16* invFh  = fwdFl + 589824;
  u16* invFl  = invFh + 589824;
  u16* skwh   = invFl + 589824;
  u16* skwl   = skwh + 16384;
  float* latb = (float*)coefh;   // alias: latb dead before coef first written

  k_tables<<<(TPAD_*64 + 255)/256, 256, 0, stream>>>(fwdFh, fwdFl, invFh, invFl);
  k_prep<<<(NL_*64*64 + 255)/256, 256, 0, stream>>>(skw, skwh, skwl);
  k_embed<<<B_, 128, 0, stream>>>(pp, ew1, eb1, ew2, eb2, ew3, eb3, lw1, lb1, latb);
  k_lift<<<dim3(TPAD_/128, B_), 128, 0, stream>>>(vterm, latb, lw1, lw2, lb2, x);
  for(int l=0;l<NL_;l++){
    k_dft_mfma<<<dim3(B_, KSPLIT), 256, 0, stream>>>(x, invFh, invFl, xfp);
    k_spectral<<<dim3(B_, 2), 512, 0, stream>>>(xfp, swr, swi, coefh, coefl, l);
    k_idft_mfma<<<dim3(TPAD_/128, B_), 256, 0, stream>>>(
        x, coefh, coefl, fwdFh, fwdFl, skwh, skwl, skb, l);
  }
  k_proj<<<dim3(T_/128, B_), 256, 0, stream>>>(x, pw1, pb1, pw2, pb2, out);
}